// Round 14
// baseline (939.771 us; speedup 1.0000x reference)
//
#include <hip/hip_runtime.h>
#include <hip/hip_fp8.h>
#include <math.h>

typedef unsigned char  u8;
typedef unsigned short u16;
typedef unsigned int   u32;
typedef long long      i64;
typedef __attribute__((ext_vector_type(4))) float f32x4;
typedef __attribute__((ext_vector_type(8))) short bf16x8;

#define M_TOK 50176
#define CDIM  384

__device__ __forceinline__ u16 f2b(float f){
  union { float f; u32 u; } v; v.f = f;
  u32 r = v.u + 0x7fffu + ((v.u >> 16) & 1u);
  return (u16)(r >> 16);
}
__device__ __forceinline__ u32 pack2(float a, float b){
  return (u32)f2b(a) | ((u32)f2b(b) << 16);
}
__device__ __forceinline__ u8 f2q(float v){          // f32 -> fp8 e4m3 (OCP)
  __hip_fp8_e4m3 t(v);
  return *reinterpret_cast<u8*>(&t);
}
// tanh-form GELU via hardware exp; |dev| vs exact erf-GELU < 3.5e-4
// (negligible under fp8-e4m3 quantization of h). NaN-safe at +-inf exp.
__device__ __forceinline__ float gelu(float x){
  float u = x * (0.7978845608028654f + 0.035677408136300125f * x * x);
  float e = __expf(2.f * u);
  float th = 1.f - 2.f / (e + 1.f);
  return 0.5f * x * (1.f + th);
}

__device__ __forceinline__ void gload_lds16(const void* g, void* l){
  __builtin_amdgcn_global_load_lds((const __attribute__((address_space(1))) u32*)g,
                                   (__attribute__((address_space(3))) u32*)l, 16, 0, 0);
}

// ---------------- weight convert f32 -> bf16 ----------------
__global__ void cvtw(const float* __restrict__ in, u16* __restrict__ out, int n4){
  int i = blockIdx.x * 256 + threadIdx.x;
  if (i < n4){
    float4 v = ((const float4*)in)[i];
    uint2 o; o.x = pack2(v.x, v.y); o.y = pack2(v.z, v.w);
    ((uint2*)out)[i] = o;
  }
}
// ---------------- weight convert f32 -> fp8 e4m3 (natural order) --------
__global__ void cvtw8(const float* __restrict__ in, u8* __restrict__ out, int n4){
  int i = blockIdx.x * 256 + threadIdx.x;
  if (i < n4){
    float4 v = ((const float4*)in)[i];
    u32 o = (u32)f2q(v.x) | ((u32)f2q(v.y) << 8) |
            ((u32)f2q(v.z) << 16) | ((u32)f2q(v.w) << 24);
    ((u32*)out)[i] = o;
  }
}
// ---------------- weight convert f32 -> fp8 with per-64 k-permutation ----
// out[row][g*64 + (j%16)*4 + j/16] = fp8(in[row][g*64 + j]).
// Matches FC1's permuted-h store order; since h (A) and W2 (B) share the
// same k-bijection, FC2's dot products are unchanged.
__global__ void cvtw8p(const float* __restrict__ in, u8* __restrict__ out,
                       int rows, int cols){
  int idx = blockIdx.x * 256 + threadIdx.x;      // output u32 index
  if (idx < rows * (cols >> 2)){
    int byte0 = idx << 2;
    int row = byte0 / cols, cb = byte0 % cols;
    int g = cb >> 6, s = (cb & 63) >> 2;         // pos 4s+m <- j = m*16+s
    const float* rp = in + (size_t)row * cols + g*64;
    u32 w = (u32)f2q(rp[s]) | ((u32)f2q(rp[16 + s]) << 8) |
            ((u32)f2q(rp[32 + s]) << 16) | ((u32)f2q(rp[48 + s]) << 24);
    ((u32*)out)[idx] = w;
  }
}

// ---------------- LayerNorm (fp32 in, bf16 or fp8 out) ----------------
template<int F8>
__global__ __launch_bounds__(256) void ln_kernel(
    const float* __restrict__ x, const float* __restrict__ g,
    const float* __restrict__ b, void* __restrict__ out, int ntok)
{
  int wave = threadIdx.x >> 6, lane = threadIdx.x & 63;
  for (long t = blockIdx.x * 4 + wave; t < ntok; t += (long)gridDim.x * 4){
    const float* xr = x + t * CDIM;
    float v[6]; float s = 0.f, ss = 0.f;
    #pragma unroll
    for (int j = 0; j < 6; ++j){ v[j] = xr[j*64 + lane]; s += v[j]; ss += v[j]*v[j]; }
    #pragma unroll
    for (int o = 32; o >= 1; o >>= 1){ s += __shfl_xor(s, o); ss += __shfl_xor(ss, o); }
    float mean = s * (1.f/384.f);
    float var  = ss * (1.f/384.f) - mean*mean;
    float rs   = rsqrtf(var + 1e-5f);
    #pragma unroll
    for (int j = 0; j < 6; ++j){
      int c = j*64 + lane;
      float val = (v[j] - mean) * rs * g[c] + b[c];
      if (F8) ((u8*)out)[t*CDIM + c] = f2q(val);
      else    ((u16*)out)[t*CDIM + c] = f2b(val);
    }
  }
}

// ---------------- bf16 GEMM (R6 proven, verbatim) ----------------
// EPI 0: bf16 store (bias)   2: f32 store (bias + resid)
template<int EPI>
__global__ __launch_bounds__(256, 4) void gemm_bt(
    const u16* __restrict__ A, const u16* __restrict__ Wt,
    const float* __restrict__ bias, const float* __restrict__ resid,
    void* __restrict__ outp, int M, int N, int K)
{
  __shared__ __align__(16) u16 smem[16384];   // 32 KB: [A0|A1|B0|B1] / epi 128x128
  const int tid  = threadIdx.x;
  const int wave = tid >> 6, lane = tid & 63;
  const int nbn  = N >> 7;
  const int nwg = gridDim.x;
  const int q8 = nwg >> 3, r8 = nwg & 7, xcd = blockIdx.x & 7, o8 = blockIdx.x >> 3;
  const int sid = (xcd < r8 ? xcd*(q8+1) : r8*(q8+1) + (xcd-r8)*q8) + o8;
  const int bm = sid / nbn, bn = sid % nbn;
  const int wr = wave >> 1, wc = wave & 1;
  const int l15 = lane & 15, l4 = lane >> 4;
  const int srow = tid >> 2, sch = tid & 3;

  f32x4 acc[4][4] = {};

  auto STAGE = [&](int buf, int kt){
    u16* lAp = smem + buf*4096;
    u16* lBp = smem + 8192 + buf*4096;
    #pragma unroll
    for (int it = 0; it < 2; ++it){
      int row = it*64 + srow;
      int chs = sch ^ ((srow >> 1) & 3);
      const u16* ga = A  + (size_t)(bm*128 + row) * K + kt + chs*8;
      const u16* gb = Wt + (size_t)(bn*128 + row) * K + kt + chs*8;
      gload_lds16(ga, &lAp[(it*256 + wave*64) * 8]);
      gload_lds16(gb, &lBp[(it*256 + wave*64) * 8]);
    }
  };

  const int NK = K >> 5;
  STAGE(0, 0);

  int cur = 0;
  for (int ki = 0; ki < NK; ++ki){
    if (ki + 1 < NK){
      STAGE(cur ^ 1, (ki + 1) * 32);
      asm volatile("s_waitcnt vmcnt(4)" ::: "memory");
    } else {
      asm volatile("s_waitcnt vmcnt(0)" ::: "memory");
    }
    __builtin_amdgcn_s_barrier();
    const u16* lAp = smem + cur*4096;
    const u16* lBp = smem + 8192 + cur*4096;
    bf16x8 af[4], bfr[4];
    const int rc = (l4 ^ ((l15 >> 1) & 3)) * 8;
    #pragma unroll
    for (int mi = 0; mi < 4; ++mi)
      af[mi] = *(const bf16x8*)&lAp[(wr*64 + mi*16 + l15)*32 + rc];
    #pragma unroll
    for (int ni = 0; ni < 4; ++ni)
      bfr[ni] = *(const bf16x8*)&lBp[(wc*64 + ni*16 + l15)*32 + rc];
    #pragma unroll
    for (int mi = 0; mi < 4; ++mi)
      #pragma unroll
      for (int ni = 0; ni < 4; ++ni)
        acc[mi][ni] = __builtin_amdgcn_mfma_f32_16x16x32_bf16(af[mi], bfr[ni], acc[mi][ni], 0, 0, 0);
    __builtin_amdgcn_s_barrier();
    cur ^= 1;
  }

  if (EPI == 2){
    #pragma unroll
    for (int ni = 0; ni < 4; ++ni){
      int col = bn*128 + wc*64 + ni*16 + l15;
      float bb = bias[col];
      #pragma unroll
      for (int mi = 0; mi < 4; ++mi){
        int row0 = bm*128 + wr*64 + mi*16 + l4*4;
        #pragma unroll
        for (int r = 0; r < 4; ++r){
          long off = (long)(row0 + r) * N + col;
          ((float*)outp)[off] = resid[off] + acc[mi][ni][r] + bb;
        }
      }
    }
  } else {
    #pragma unroll
    for (int ni = 0; ni < 4; ++ni){
      int colL = wc*64 + ni*16 + l15;
      float bb = bias[bn*128 + colL];
      int colS = colL ^ (l4*16);
      #pragma unroll
      for (int mi = 0; mi < 4; ++mi){
        int rowL = wr*64 + mi*16 + l4*4;
        #pragma unroll
        for (int r = 0; r < 4; ++r){
          float v = acc[mi][ni][r] + bb;
          smem[(rowL + r)*128 + colS] = f2b(v);
        }
      }
    }
    __syncthreads();
    const u32* eb = (const u32*)smem;
    u32* og = (u32*)outp;
    const int nW = N >> 1;
    #pragma unroll
    for (int it = 0; it < 32; ++it){
      int row = wave*32 + it;
      u32 w = eb[row*64 + (lane ^ (((row >> 2) & 3) * 8))];
      __builtin_nontemporal_store(w, &og[(size_t)(bm*128 + row) * nW + bn*64 + lane]);
    }
  }
}

// ---------------- fp8 GEMM: R6 shell, half staged bytes, conflict-free ----
// 16B slots permuted by involution slot' = s ^ ((s>>3)&7) on stage-source
// AND frag read -> 2-way bank aliasing (free).
// EPI 1: h out (bias + exp-GELU) packed 4x fp8 -> one u32/lane, stored in
//        per-64-col PERMUTED order (pos = (j%16)*4 + j/16): quarter-wave =
//        one full 64B line, no LDS bounce, no conflicts. W2 pre-permuted to
//        match (cvtw8p) so FC2 is numerically identical.
// EPI 2: f32 bias+resid direct.
template<int EPI>
__global__ __launch_bounds__(256, 4) void gemm_f8(
    const u8* __restrict__ A, const u8* __restrict__ Wt,
    const float* __restrict__ bias, const float* __restrict__ resid,
    void* __restrict__ outp, int M, int N, int K)
{
  __shared__ __align__(16) u8 smem[16384];    // 2 bufs x (A 4KB + B 4KB)
  const int tid  = threadIdx.x;
  const int wave = tid >> 6, lane = tid & 63;
  const int nbn  = N >> 7;
  const int nwg = gridDim.x;
  const int q8 = nwg >> 3, r8 = nwg & 7, xcd = blockIdx.x & 7, o8 = blockIdx.x >> 3;
  const int sid = (xcd < r8 ? xcd*(q8+1) : r8*(q8+1) + (xcd-r8)*q8) + o8;
  const int bm = sid / nbn, bn = sid % nbn;
  const int wr = wave >> 1, wc = wave & 1;
  const int l15 = lane & 15, l4 = lane >> 4;

  f32x4 acc[4][4] = {};

  const int gsl = tid ^ ((tid >> 3) & 7);     // involution: global chunk for slot tid
  const int grow = gsl >> 1, gc16 = gsl & 1;

  auto STAGE = [&](int buf, int kt){          // 2 gload_lds16 per thread
    const u8* ga = A  + (size_t)(bm*128 + grow) * K + kt + gc16*16;
    const u8* gb = Wt + (size_t)(bn*128 + grow) * K + kt + gc16*16;
    gload_lds16(ga, &smem[buf*8192 + tid*16]);
    gload_lds16(gb, &smem[buf*8192 + 4096 + tid*16]);
  };

  const int NK = K >> 5;
  STAGE(0, 0);

  // per-thread frag slot offsets (loop-invariant)
  const int c16 = l4 >> 1, half8 = (l4 & 1) * 8;
  int spA[4], spB[4];
  #pragma unroll
  for (int mi = 0; mi < 4; ++mi){
    int s = (wr*64 + mi*16 + l15)*2 + c16;
    spA[mi] = (s ^ ((s >> 3) & 7)) * 16 + half8;
  }
  #pragma unroll
  for (int ni = 0; ni < 4; ++ni){
    int s = (wc*64 + ni*16 + l15)*2 + c16;
    spB[ni] = (s ^ ((s >> 3) & 7)) * 16 + half8;
  }

  int cur = 0;
  for (int ki = 0; ki < NK; ++ki){
    if (ki + 1 < NK){
      STAGE(cur ^ 1, (ki + 1) * 32);
      asm volatile("s_waitcnt vmcnt(2)" ::: "memory");  // prev stage done
    } else {
      asm volatile("s_waitcnt vmcnt(0)" ::: "memory");
    }
    __builtin_amdgcn_s_barrier();
    const u8* lAp = smem + cur*8192;
    const u8* lBp = smem + cur*8192 + 4096;
    i64 af[4], bf[4];
    #pragma unroll
    for (int mi = 0; mi < 4; ++mi)
      af[mi] = *(const i64*)&lAp[spA[mi]];
    #pragma unroll
    for (int ni = 0; ni < 4; ++ni)
      bf[ni] = *(const i64*)&lBp[spB[ni]];
    #pragma unroll
    for (int mi = 0; mi < 4; ++mi)
      #pragma unroll
      for (int ni = 0; ni < 4; ++ni)
        acc[mi][ni] = __builtin_amdgcn_mfma_f32_16x16x32_fp8_fp8(af[mi], bf[ni], acc[mi][ni], 0, 0, 0);
    __builtin_amdgcn_s_barrier();
    cur ^= 1;
  }

  if (EPI == 2){
    // f32 + residual: 16 lanes x 4B = full 64B lines
    #pragma unroll
    for (int ni = 0; ni < 4; ++ni){
      int col = bn*128 + wc*64 + ni*16 + l15;
      float bb = bias[col];
      #pragma unroll
      for (int mi = 0; mi < 4; ++mi){
        int row0 = bm*128 + wr*64 + mi*16 + l4*4;
        #pragma unroll
        for (int r = 0; r < 4; ++r){
          long off = (long)(row0 + r) * N + col;
          ((float*)outp)[off] = resid[off] + acc[mi][ni][r] + bb;
        }
      }
    }
  } else {
    // h out (bias + GELU), permuted-order packed u32 direct NT stores.
    // lane's 4 ni-values (cols wc*64 + ni*16 + l15) -> byte pos
    // wc*64 + l15*4 + ni of the row. Quarter-wave = 64B full line.
    u32* og = (u32*)outp;
    const int nW = N >> 2;
    float bb[4];
    #pragma unroll
    for (int ni = 0; ni < 4; ++ni) bb[ni] = bias[bn*128 + wc*64 + ni*16 + l15];
    const int wordc = (bn*128 + wc*64 + l15*4) >> 2;
    #pragma unroll
    for (int mi = 0; mi < 4; ++mi){
      int row0 = bm*128 + wr*64 + mi*16 + l4*4;
      #pragma unroll
      for (int r = 0; r < 4; ++r){
        u32 w = 0;
        #pragma unroll
        for (int ni = 0; ni < 4; ++ni){
          float v = gelu(acc[mi][ni][r] + bb[ni]);
          w |= (u32)f2q(v) << (8*ni);
        }
        __builtin_nontemporal_store(w, &og[(size_t)(row0 + r) * nW + wordc]);
      }
    }
  }
}

// ---------------- bias table (fragment order) ----------------
__global__ void build_btbl(const float* __restrict__ rpb, const int* __restrict__ ridx,
                           float* __restrict__ btbl){
  int q = blockIdx.x & 63, h = blockIdx.x >> 6;
  int l = threadIdx.x;
  float v = -1e9f;
  if (q < 49){
    int key = (l & 3) * 16 + (l >> 2);
    if (key < 49) v = rpb[ridx[q*49 + key] * 12 + h];
  }
  btbl[(h*64 + q)*64 + l] = v;
}

// ---------------- MFMA windowed attention (unchanged) ----------------
template<int SHIFT>
__global__ __launch_bounds__(64) void attn_mfma(
    const u16* __restrict__ qkv, const float* __restrict__ btbl,
    u16* __restrict__ attn_out)
{
  __shared__ __align__(16) u16 p_lds[64*72];
  __shared__ __align__(16) u16 vt_lds[32*72];
  __shared__ int tok_lds[64];
  __shared__ int rid_lds[64];

  const int bid = blockIdx.x;
  const int h   = bid % 12;
  const int win = bid / 12;
  const int b   = win >> 6, wl = win & 63;
  const int wy  = wl >> 3,  wx = wl & 7;
  const int lane = threadIdx.x;
  const int l15 = lane & 15, l4 = lane >> 4;

  auto tokof = [&](int n)->int{
    int r = (n * 9363) >> 16;
    int c = n - r * 7;
    int hh = wy*7 + r + SHIFT; if (hh >= 56) hh -= 56;
    int ww = wx*7 + c + SHIFT; if (ww >= 56) ww -= 56;
    return b*3136 + hh*56 + ww;
  };

  {
    const int n  = lane;
    const int nc = n < 49 ? n : 48;
    const int t  = tokof(nc);
    tok_lds[n] = t;
    if (SHIFT){
      int r = (nc * 9363) >> 16, c = nc - r*7;
      int gh = wy*7 + r, gw = wx*7 + c;
      int rh = gh <= 48 ? 0 : (gh <= 52 ? 1 : 2);
      int rw = gw <= 48 ? 0 : (gw <= 52 ? 1 : 2);
      rid_lds[n] = rh*3 + rw;
    }
    const uint4* vp = (const uint4*)(qkv + (size_t)t*1152 + 768 + h*32);
    u32 w[16];
    #pragma unroll
    for (int j4 = 0; j4 < 4; ++j4){
      uint4 u = vp[j4];
      w[j4*4+0]=u.x; w[j4*4+1]=u.y; w[j4*4+2]=u.z; w[j4*4+3]=u.w;
    }
    if (n >= 49){
      #pragma unroll
      for (int j = 0; j < 16; ++j) w[j] = 0;
    }
    #pragma unroll
    for (int j = 0; j < 16; ++j){
      vt_lds[(2*j  )*72 + n] = (u16)(w[j] & 0xffffu);
      vt_lds[(2*j+1)*72 + n] = (u16)(w[j] >> 16);
    }
  }

  bf16x8 qa[4], kb[4];
  #pragma unroll
  for (int mi = 0; mi < 4; ++mi){
    int row = mi*16 + l15; int t = tokof(row < 49 ? row : 48);
    qa[mi] = *(const bf16x8*)(qkv + (size_t)t*1152 + h*32 + l4*8);
  }
  #pragma unroll
  for (int ni = 0; ni < 4; ++ni){
    int row = ni*16 + l15; int t = tokof(row < 49 ? row : 48);
    kb[ni] = *(const bf16x8*)(qkv + (size_t)t*1152 + 384 + h*32 + l4*8);
  }
  f32x4 s[4][4] = {};
  #pragma unroll
  for (int mi = 0; mi < 4; ++mi)
    #pragma unroll
    for (int ni = 0; ni < 4; ++ni)
      s[mi][ni] = __builtin_amdgcn_mfma_f32_16x16x32_bf16(qa[mi], kb[ni], s[mi][ni], 0, 0, 0);

  __syncthreads();

  int rid_k[4];
  if (SHIFT){
    #pragma unroll
    for (int ni = 0; ni < 4; ++ni) rid_k[ni] = rid_lds[ni*16 + l15];
  }

  const float* bt = btbl + h*4096;
  float den[4][4];
  #pragma unroll
  for (int mi = 0; mi < 4; ++mi){
    #pragma unroll
    for (int r = 0; r < 4; ++r){
      int q = mi*16 + l4*4 + r;
      f32x4 bq = *(const f32x4*)(bt + q*64 + l15*4);
      int ridq = 0;
      if (SHIFT) ridq = rid_lds[q];
      #pragma unroll
      for (int ni = 0; ni < 4; ++ni){
        float v = s[mi][ni][r] * 0.17677669529663687f + bq[ni];
        if (SHIFT) v += (ridq == rid_k[ni]) ? 0.f : -100.f;
        s[mi][ni][r] = v;
      }
      float m0 = fmaxf(fmaxf(s[mi][0][r], s[mi][1][r]), fmaxf(s[mi][2][r], s[mi][3][r]));
      #pragma unroll
      for (int o = 1; o <= 8; o <<= 1) m0 = fmaxf(m0, __shfl_xor(m0, o));
      float d0 = 0.f;
      #pragma unroll
      for (int ni = 0; ni < 4; ++ni){
        float e = __expf(s[mi][ni][r] - m0);
        s[mi][ni][r] = e; d0 += e;
      }
      #pragma unroll
      for (int o = 1; o <= 8; o <<= 1) d0 += __shfl_xor(d0, o);
      den[mi][r] = d0;
    }
  }

  #pragma unroll
  for (int mi = 0; mi < 4; ++mi)
    #pragma unroll
    for (int r = 0; r < 4; ++r){
      int q = mi*16 + l4*4 + r;
      #pragma unroll
      for (int ni = 0; ni < 4; ++ni)
        p_lds[q*72 + ni*16 + l15] = f2b(s[mi][ni][r]);
    }

  __syncthreads();

  f32x4 o2[4][2] = {};
  #pragma unroll
  for (int ks = 0; ks < 2; ++ks){
    bf16x8 vb[2];
    #pragma unroll
    for (int ni = 0; ni < 2; ++ni)
      vb[ni] = *(const bf16x8*)&vt_lds[(ni*16 + l15)*72 + ks*32 + l4*8];
    #pragma unroll
    for (int mi = 0; mi < 4; ++mi){
      bf16x8 pa = *(const bf16x8*)&p_lds[(mi*16 + l15)*72 + ks*32 + l4*8];
      #pragma unroll
      for (int ni = 0; ni < 2; ++ni)
        o2[mi][ni] = __builtin_amdgcn_mfma_f32_16x16x32_bf16(pa, vb[ni], o2[mi][ni], 0, 0, 0);
    }
  }

  #pragma unroll
  for (int mi = 0; mi < 4; ++mi){
    #pragma unroll
    for (int r = 0; r < 4; ++r){
      int q = mi*16 + l4*4 + r;
      if (q < 49){
        float inv = 1.f / den[mi][r];
        long t = tok_lds[q];
        #pragma unroll
        for (int ni = 0; ni < 2; ++ni){
          int d = ni*16 + l15;
          attn_out[t*384 + h*32 + d] = f2b(o2[mi][ni][r] * inv);
        }
      }
    }
  }
}

extern "C" void kernel_launch(void* const* d_in, const int* in_sizes, int n_in,
                              void* d_out, int out_size, void* d_ws, size_t ws_size,
                              hipStream_t stream)
{
  const float* x_in   = (const float*)d_in[0];
  const int*   relidx = (const int*)d_in[2];
  const float* n1g    = (const float*)d_in[3];
  const float* n1b    = (const float*)d_in[4];
  const float* qkvw   = (const float*)d_in[5];
  const float* qkvb   = (const float*)d_in[6];
  const float* rpb    = (const float*)d_in[7];
  const float* pw     = (const float*)d_in[8];
  const float* pb     = (const float*)d_in[9];
  const float* n2g    = (const float*)d_in[10];
  const float* n2b    = (const float*)d_in[11];
  const float* f1w    = (const float*)d_in[12];
  const float* f1b    = (const float*)d_in[13];
  const float* f2w    = (const float*)d_in[14];
  const float* f2bb   = (const float*)d_in[15];
  float* xout = (float*)d_out;

  char* ws = (char*)d_ws;
  u16* wqkv   = (u16*)ws; ws += (size_t)2*1152*384*2;
  u16* wproj  = (u16*)ws; ws += (size_t)2*384*384*2;
  u8*  wfc1q  = (u8*)ws;  ws += (size_t)2*1536*384;
  u8*  wfc2q  = (u8*)ws;  ws += (size_t)2*384*1536;
  u16* bufA   = (u16*)ws; ws += (size_t)M_TOK*1536*2;  // qkv bf16 / h fp8 overlay
  u16* bufB   = (u16*)ws; ws += (size_t)M_TOK*384*2;   // LN1 bf16 / attn_out bf16
  u8*  bufD   = (u8*)ws;  ws += (size_t)M_TOK*384;     // LN2 fp8
  float* btbl = (float*)(bufA + (size_t)M_TOK*1152);   // tail of bufA during attn
  u8* h8 = (u8*)bufA;                                  // FC1 out overlays qkv

  // convert weights: qkv/proj -> bf16; fc1 -> fp8; fc2 -> fp8 k-permuted
  {
    int n;
    n = 2*1152*384;  cvtw  <<<dim3((n/4+255)/256), dim3(256), 0, stream>>>(qkvw, wqkv,  n/4);
    n = 2*384*384;   cvtw  <<<dim3((n/4+255)/256), dim3(256), 0, stream>>>(pw,   wproj, n/4);
    n = 2*1536*384;  cvtw8 <<<dim3((n/4+255)/256), dim3(256), 0, stream>>>(f1w,  wfc1q, n/4);
    n = 2*384*1536;  cvtw8p<<<dim3((n/4+255)/256), dim3(256), 0, stream>>>(f2w,  wfc2q, 2*384, 1536);
  }

  for (int i = 0; i < 2; ++i){
    const float* xi = (i == 0) ? x_in : xout;
    // LN1 -> bufB (bf16)
    ln_kernel<0><<<dim3(2048), dim3(256), 0, stream>>>(xi, n1g + i*384, n1b + i*384, bufB, M_TOK);
    // QKV (bf16): bufB @ wqkv^T -> bufA  [M,1152]   grid 3528
    gemm_bt<0><<<dim3(3528), dim3(256), 0, stream>>>(
        bufB, wqkv + (size_t)i*1152*384, qkvb + i*1152, nullptr, bufA, M_TOK, 1152, 384);
    // bias table
    build_btbl<<<dim3(768), dim3(64), 0, stream>>>(rpb + (size_t)i*169*12, relidx, btbl);
    // attention: bufA -> bufB [M,384] bf16
    if (i == 0)
      attn_mfma<0><<<dim3(12288), dim3(64), 0, stream>>>(bufA, btbl, bufB);
    else
      attn_mfma<3><<<dim3(12288), dim3(64), 0, stream>>>(bufA, btbl, bufB);
    // proj + residual (bf16): xout = xi + bufB @ wproj^T + pb   grid 1176
    gemm_bt<2><<<dim3(1176), dim3(256), 0, stream>>>(
        bufB, wproj + (size_t)i*384*384, pb + i*384, xi, xout, M_TOK, 384, 384);
    // LN2 -> bufD (fp8)
    ln_kernel<1><<<dim3(2048), dim3(256), 0, stream>>>(xout, n2g + i*384, n2b + i*384, bufD, M_TOK);
    // FC1 (fp8) + gelu: bufD @ wfc1q^T -> h8 [M,1536] fp8 (permuted cols)  grid 4704
    gemm_f8<1><<<dim3(4704), dim3(256), 0, stream>>>(
        bufD, wfc1q + (size_t)i*1536*384, f1b + i*1536, nullptr, h8, M_TOK, 1536, 384);
    // FC2 (fp8, k-permuted both sides) + residual: xout += h8 @ wfc2q^T + f2b  grid 1176
    gemm_f8<2><<<dim3(1176), dim3(256), 0, stream>>>(
        h8, wfc2q + (size_t)i*384*1536, f2bb + i*384, xout, xout, M_TOK, 384, 1536);
  }
  (void)in_sizes; (void)n_in; (void)out_size; (void)ws_size;
}

// Round 15
// 928.137 us; speedup vs baseline: 1.0125x; 1.0125x over previous
//
#include <hip/hip_runtime.h>
#include <hip/hip_fp8.h>
#include <math.h>

typedef unsigned char  u8;
typedef unsigned short u16;
typedef unsigned int   u32;
typedef long long      i64;
typedef __attribute__((ext_vector_type(4))) float f32x4;
typedef __attribute__((ext_vector_type(8))) short bf16x8;

#define M_TOK 50176
#define CDIM  384

__device__ __forceinline__ u16 f2b(float f){
  union { float f; u32 u; } v; v.f = f;
  u32 r = v.u + 0x7fffu + ((v.u >> 16) & 1u);
  return (u16)(r >> 16);
}
__device__ __forceinline__ u32 pack2(float a, float b){
  return (u32)f2b(a) | ((u32)f2b(b) << 16);
}
__device__ __forceinline__ u8 f2q(float v){          // f32 -> fp8 e4m3 (OCP), cold paths only
  __hip_fp8_e4m3 t(v);
  return *reinterpret_cast<u8*>(&t);
}
// HW packed f32x2 -> 2 fp8 bytes (OCP e4m3 on gfx950). byte0 = a, byte1 = b.
__device__ __forceinline__ u32 cvt2q(float a, float b){
  u32 p = 0;
  asm("v_cvt_pk_fp8_f32 %0, %1, %2" : "+v"(p) : "v"(a), "v"(b));
  return p & 0xffffu;
}
// tanh-form GELU via hardware exp; |dev| vs exact erf-GELU < 3.5e-4
// (negligible under fp8-e4m3 quantization of h). NaN-safe at +-inf exp.
__device__ __forceinline__ float gelu(float x){
  float u = x * (0.7978845608028654f + 0.035677408136300125f * x * x);
  float e = __expf(2.f * u);
  float th = 1.f - 2.f / (e + 1.f);
  return 0.5f * x * (1.f + th);
}

__device__ __forceinline__ void gload_lds16(const void* g, void* l){
  __builtin_amdgcn_global_load_lds((const __attribute__((address_space(1))) u32*)g,
                                   (__attribute__((address_space(3))) u32*)l, 16, 0, 0);
}

// ---------------- weight convert f32 -> bf16 ----------------
__global__ void cvtw(const float* __restrict__ in, u16* __restrict__ out, int n4){
  int i = blockIdx.x * 256 + threadIdx.x;
  if (i < n4){
    float4 v = ((const float4*)in)[i];
    uint2 o; o.x = pack2(v.x, v.y); o.y = pack2(v.z, v.w);
    ((uint2*)out)[i] = o;
  }
}
// ---------------- weight convert f32 -> fp8 e4m3 (natural order) --------
__global__ void cvtw8(const float* __restrict__ in, u8* __restrict__ out, int n4){
  int i = blockIdx.x * 256 + threadIdx.x;
  if (i < n4){
    float4 v = ((const float4*)in)[i];
    u32 o = cvt2q(v.x, v.y) | (cvt2q(v.z, v.w) << 16);
    ((u32*)out)[i] = o;
  }
}
// ---------------- weight convert f32 -> fp8 with per-64 k-permutation ----
// out[row][g*64 + (j%16)*4 + j/16] = fp8(in[row][g*64 + j]).
// Matches FC1's permuted-h store order; since h (A) and W2 (B) share the
// same k-bijection, FC2's dot products are unchanged.
__global__ void cvtw8p(const float* __restrict__ in, u8* __restrict__ out,
                       int rows, int cols){
  int idx = blockIdx.x * 256 + threadIdx.x;      // output u32 index
  if (idx < rows * (cols >> 2)){
    int byte0 = idx << 2;
    int row = byte0 / cols, cb = byte0 % cols;
    int g = cb >> 6, s = (cb & 63) >> 2;         // pos 4s+m <- j = m*16+s
    const float* rp = in + (size_t)row * cols + g*64;
    u32 w = cvt2q(rp[s], rp[16 + s]) | (cvt2q(rp[32 + s], rp[48 + s]) << 16);
    ((u32*)out)[idx] = w;
  }
}

// ---------------- LayerNorm (fp32 in, bf16 or fp8 out) ----------------
template<int F8>
__global__ __launch_bounds__(256) void ln_kernel(
    const float* __restrict__ x, const float* __restrict__ g,
    const float* __restrict__ b, void* __restrict__ out, int ntok)
{
  int wave = threadIdx.x >> 6, lane = threadIdx.x & 63;
  for (long t = blockIdx.x * 4 + wave; t < ntok; t += (long)gridDim.x * 4){
    const float* xr = x + t * CDIM;
    float v[6]; float s = 0.f, ss = 0.f;
    #pragma unroll
    for (int j = 0; j < 6; ++j){ v[j] = xr[j*64 + lane]; s += v[j]; ss += v[j]*v[j]; }
    #pragma unroll
    for (int o = 32; o >= 1; o >>= 1){ s += __shfl_xor(s, o); ss += __shfl_xor(ss, o); }
    float mean = s * (1.f/384.f);
    float var  = ss * (1.f/384.f) - mean*mean;
    float rs   = rsqrtf(var + 1e-5f);
    if (F8){
      float nv[6];
      #pragma unroll
      for (int j = 0; j < 6; ++j){
        int c = j*64 + lane;
        nv[j] = (v[j] - mean) * rs * g[c] + b[c];
      }
      #pragma unroll
      for (int j = 0; j < 6; j += 2){
        u32 p = cvt2q(nv[j], nv[j+1]);           // HW packed convert
        ((u8*)out)[t*CDIM + j*64 + lane]     = (u8)(p & 0xff);
        ((u8*)out)[t*CDIM + (j+1)*64 + lane] = (u8)((p >> 8) & 0xff);
      }
    } else {
      #pragma unroll
      for (int j = 0; j < 6; ++j){
        int c = j*64 + lane;
        ((u16*)out)[t*CDIM + c] = f2b((v[j] - mean) * rs * g[c] + b[c]);
      }
    }
  }
}

// ---------------- bf16 GEMM (R6 proven, verbatim) ----------------
// EPI 0: bf16 store (bias)   2: f32 store (bias + resid)
template<int EPI>
__global__ __launch_bounds__(256, 4) void gemm_bt(
    const u16* __restrict__ A, const u16* __restrict__ Wt,
    const float* __restrict__ bias, const float* __restrict__ resid,
    void* __restrict__ outp, int M, int N, int K)
{
  __shared__ __align__(16) u16 smem[16384];   // 32 KB: [A0|A1|B0|B1] / epi 128x128
  const int tid  = threadIdx.x;
  const int wave = tid >> 6, lane = tid & 63;
  const int nbn  = N >> 7;
  const int nwg = gridDim.x;
  const int q8 = nwg >> 3, r8 = nwg & 7, xcd = blockIdx.x & 7, o8 = blockIdx.x >> 3;
  const int sid = (xcd < r8 ? xcd*(q8+1) : r8*(q8+1) + (xcd-r8)*q8) + o8;
  const int bm = sid / nbn, bn = sid % nbn;
  const int wr = wave >> 1, wc = wave & 1;
  const int l15 = lane & 15, l4 = lane >> 4;
  const int srow = tid >> 2, sch = tid & 3;

  f32x4 acc[4][4] = {};

  auto STAGE = [&](int buf, int kt){
    u16* lAp = smem + buf*4096;
    u16* lBp = smem + 8192 + buf*4096;
    #pragma unroll
    for (int it = 0; it < 2; ++it){
      int row = it*64 + srow;
      int chs = sch ^ ((srow >> 1) & 3);
      const u16* ga = A  + (size_t)(bm*128 + row) * K + kt + chs*8;
      const u16* gb = Wt + (size_t)(bn*128 + row) * K + kt + chs*8;
      gload_lds16(ga, &lAp[(it*256 + wave*64) * 8]);
      gload_lds16(gb, &lBp[(it*256 + wave*64) * 8]);
    }
  };

  const int NK = K >> 5;
  STAGE(0, 0);

  int cur = 0;
  for (int ki = 0; ki < NK; ++ki){
    if (ki + 1 < NK){
      STAGE(cur ^ 1, (ki + 1) * 32);
      asm volatile("s_waitcnt vmcnt(4)" ::: "memory");
    } else {
      asm volatile("s_waitcnt vmcnt(0)" ::: "memory");
    }
    __builtin_amdgcn_s_barrier();
    const u16* lAp = smem + cur*4096;
    const u16* lBp = smem + 8192 + cur*4096;
    bf16x8 af[4], bfr[4];
    const int rc = (l4 ^ ((l15 >> 1) & 3)) * 8;
    #pragma unroll
    for (int mi = 0; mi < 4; ++mi)
      af[mi] = *(const bf16x8*)&lAp[(wr*64 + mi*16 + l15)*32 + rc];
    #pragma unroll
    for (int ni = 0; ni < 4; ++ni)
      bfr[ni] = *(const bf16x8*)&lBp[(wc*64 + ni*16 + l15)*32 + rc];
    #pragma unroll
    for (int mi = 0; mi < 4; ++mi)
      #pragma unroll
      for (int ni = 0; ni < 4; ++ni)
        acc[mi][ni] = __builtin_amdgcn_mfma_f32_16x16x32_bf16(af[mi], bfr[ni], acc[mi][ni], 0, 0, 0);
    __builtin_amdgcn_s_barrier();
    cur ^= 1;
  }

  if (EPI == 2){
    #pragma unroll
    for (int ni = 0; ni < 4; ++ni){
      int col = bn*128 + wc*64 + ni*16 + l15;
      float bb = bias[col];
      #pragma unroll
      for (int mi = 0; mi < 4; ++mi){
        int row0 = bm*128 + wr*64 + mi*16 + l4*4;
        #pragma unroll
        for (int r = 0; r < 4; ++r){
          long off = (long)(row0 + r) * N + col;
          ((float*)outp)[off] = resid[off] + acc[mi][ni][r] + bb;
        }
      }
    }
  } else {
    #pragma unroll
    for (int ni = 0; ni < 4; ++ni){
      int colL = wc*64 + ni*16 + l15;
      float bb = bias[bn*128 + colL];
      int colS = colL ^ (l4*16);
      #pragma unroll
      for (int mi = 0; mi < 4; ++mi){
        int rowL = wr*64 + mi*16 + l4*4;
        #pragma unroll
        for (int r = 0; r < 4; ++r){
          float v = acc[mi][ni][r] + bb;
          smem[(rowL + r)*128 + colS] = f2b(v);
        }
      }
    }
    __syncthreads();
    const u32* eb = (const u32*)smem;
    u32* og = (u32*)outp;
    const int nW = N >> 1;
    #pragma unroll
    for (int it = 0; it < 32; ++it){
      int row = wave*32 + it;
      u32 w = eb[row*64 + (lane ^ (((row >> 2) & 3) * 8))];
      __builtin_nontemporal_store(w, &og[(size_t)(bm*128 + row) * nW + bn*64 + lane]);
    }
  }
}

// ---------------- fp8 GEMM: R6 shell, half staged bytes, conflict-free ----
// 16B slots permuted by involution slot' = s ^ ((s>>3)&7) on stage-source
// AND frag read -> 2-way bank aliasing (free).
// EPI 1: h out (bias + exp-GELU) packed via HW v_cvt_pk_fp8_f32 (R14's
//        software f2q was the 65% VALUBusy hog) -> one u32/lane NT store in
//        per-64-col PERMUTED order; W2 pre-permuted to match (cvtw8p).
// EPI 2: f32 bias+resid direct.
template<int EPI>
__global__ __launch_bounds__(256, 4) void gemm_f8(
    const u8* __restrict__ A, const u8* __restrict__ Wt,
    const float* __restrict__ bias, const float* __restrict__ resid,
    void* __restrict__ outp, int M, int N, int K)
{
  __shared__ __align__(16) u8 smem[16384];    // 2 bufs x (A 4KB + B 4KB)
  const int tid  = threadIdx.x;
  const int wave = tid >> 6, lane = tid & 63;
  const int nbn  = N >> 7;
  const int nwg = gridDim.x;
  const int q8 = nwg >> 3, r8 = nwg & 7, xcd = blockIdx.x & 7, o8 = blockIdx.x >> 3;
  const int sid = (xcd < r8 ? xcd*(q8+1) : r8*(q8+1) + (xcd-r8)*q8) + o8;
  const int bm = sid / nbn, bn = sid % nbn;
  const int wr = wave >> 1, wc = wave & 1;
  const int l15 = lane & 15, l4 = lane >> 4;

  f32x4 acc[4][4] = {};

  const int gsl = tid ^ ((tid >> 3) & 7);     // involution: global chunk for slot tid
  const int grow = gsl >> 1, gc16 = gsl & 1;

  auto STAGE = [&](int buf, int kt){          // 2 gload_lds16 per thread
    const u8* ga = A  + (size_t)(bm*128 + grow) * K + kt + gc16*16;
    const u8* gb = Wt + (size_t)(bn*128 + grow) * K + kt + gc16*16;
    gload_lds16(ga, &smem[buf*8192 + tid*16]);
    gload_lds16(gb, &smem[buf*8192 + 4096 + tid*16]);
  };

  const int NK = K >> 5;
  STAGE(0, 0);

  // per-thread frag slot offsets (loop-invariant)
  const int c16 = l4 >> 1, half8 = (l4 & 1) * 8;
  int spA[4], spB[4];
  #pragma unroll
  for (int mi = 0; mi < 4; ++mi){
    int s = (wr*64 + mi*16 + l15)*2 + c16;
    spA[mi] = (s ^ ((s >> 3) & 7)) * 16 + half8;
  }
  #pragma unroll
  for (int ni = 0; ni < 4; ++ni){
    int s = (wc*64 + ni*16 + l15)*2 + c16;
    spB[ni] = (s ^ ((s >> 3) & 7)) * 16 + half8;
  }

  int cur = 0;
  for (int ki = 0; ki < NK; ++ki){
    if (ki + 1 < NK){
      STAGE(cur ^ 1, (ki + 1) * 32);
      asm volatile("s_waitcnt vmcnt(2)" ::: "memory");  // prev stage done
    } else {
      asm volatile("s_waitcnt vmcnt(0)" ::: "memory");
    }
    __builtin_amdgcn_s_barrier();
    const u8* lAp = smem + cur*8192;
    const u8* lBp = smem + cur*8192 + 4096;
    i64 af[4], bf[4];
    #pragma unroll
    for (int mi = 0; mi < 4; ++mi)
      af[mi] = *(const i64*)&lAp[spA[mi]];
    #pragma unroll
    for (int ni = 0; ni < 4; ++ni)
      bf[ni] = *(const i64*)&lBp[spB[ni]];
    #pragma unroll
    for (int mi = 0; mi < 4; ++mi)
      #pragma unroll
      for (int ni = 0; ni < 4; ++ni)
        acc[mi][ni] = __builtin_amdgcn_mfma_f32_16x16x32_fp8_fp8(af[mi], bf[ni], acc[mi][ni], 0, 0, 0);
    __builtin_amdgcn_s_barrier();
    cur ^= 1;
  }

  if (EPI == 2){
    // f32 + residual: 16 lanes x 4B = full 64B lines
    #pragma unroll
    for (int ni = 0; ni < 4; ++ni){
      int col = bn*128 + wc*64 + ni*16 + l15;
      float bb = bias[col];
      #pragma unroll
      for (int mi = 0; mi < 4; ++mi){
        int row0 = bm*128 + wr*64 + mi*16 + l4*4;
        #pragma unroll
        for (int r = 0; r < 4; ++r){
          long off = (long)(row0 + r) * N + col;
          ((float*)outp)[off] = resid[off] + acc[mi][ni][r] + bb;
        }
      }
    }
  } else {
    // h out (bias + GELU), HW packed cvt, permuted-order u32 NT stores.
    // lane's 4 ni-values -> byte pos wc*64 + l15*4 + ni of the row.
    u32* og = (u32*)outp;
    const int nW = N >> 2;
    float bb[4];
    #pragma unroll
    for (int ni = 0; ni < 4; ++ni) bb[ni] = bias[bn*128 + wc*64 + ni*16 + l15];
    const int wordc = (bn*128 + wc*64 + l15*4) >> 2;
    #pragma unroll
    for (int mi = 0; mi < 4; ++mi){
      int row0 = bm*128 + wr*64 + mi*16 + l4*4;
      #pragma unroll
      for (int r = 0; r < 4; ++r){
        float v0 = gelu(acc[mi][0][r] + bb[0]);
        float v1 = gelu(acc[mi][1][r] + bb[1]);
        float v2 = gelu(acc[mi][2][r] + bb[2]);
        float v3 = gelu(acc[mi][3][r] + bb[3]);
        u32 w = cvt2q(v0, v1) | (cvt2q(v2, v3) << 16);
        __builtin_nontemporal_store(w, &og[(size_t)(row0 + r) * nW + wordc]);
      }
    }
  }
}

// ---------------- bias table (fragment order) ----------------
__global__ void build_btbl(const float* __restrict__ rpb, const int* __restrict__ ridx,
                           float* __restrict__ btbl){
  int q = blockIdx.x & 63, h = blockIdx.x >> 6;
  int l = threadIdx.x;
  float v = -1e9f;
  if (q < 49){
    int key = (l & 3) * 16 + (l >> 2);
    if (key < 49) v = rpb[ridx[q*49 + key] * 12 + h];
  }
  btbl[(h*64 + q)*64 + l] = v;
}

// ---------------- MFMA windowed attention (unchanged) ----------------
template<int SHIFT>
__global__ __launch_bounds__(64) void attn_mfma(
    const u16* __restrict__ qkv, const float* __restrict__ btbl,
    u16* __restrict__ attn_out)
{
  __shared__ __align__(16) u16 p_lds[64*72];
  __shared__ __align__(16) u16 vt_lds[32*72];
  __shared__ int tok_lds[64];
  __shared__ int rid_lds[64];

  const int bid = blockIdx.x;
  const int h   = bid % 12;
  const int win = bid / 12;
  const int b   = win >> 6, wl = win & 63;
  const int wy  = wl >> 3,  wx = wl & 7;
  const int lane = threadIdx.x;
  const int l15 = lane & 15, l4 = lane >> 4;

  auto tokof = [&](int n)->int{
    int r = (n * 9363) >> 16;
    int c = n - r * 7;
    int hh = wy*7 + r + SHIFT; if (hh >= 56) hh -= 56;
    int ww = wx*7 + c + SHIFT; if (ww >= 56) ww -= 56;
    return b*3136 + hh*56 + ww;
  };

  {
    const int n  = lane;
    const int nc = n < 49 ? n : 48;
    const int t  = tokof(nc);
    tok_lds[n] = t;
    if (SHIFT){
      int r = (nc * 9363) >> 16, c = nc - r*7;
      int gh = wy*7 + r, gw = wx*7 + c;
      int rh = gh <= 48 ? 0 : (gh <= 52 ? 1 : 2);
      int rw = gw <= 48 ? 0 : (gw <= 52 ? 1 : 2);
      rid_lds[n] = rh*3 + rw;
    }
    const uint4* vp = (const uint4*)(qkv + (size_t)t*1152 + 768 + h*32);
    u32 w[16];
    #pragma unroll
    for (int j4 = 0; j4 < 4; ++j4){
      uint4 u = vp[j4];
      w[j4*4+0]=u.x; w[j4*4+1]=u.y; w[j4*4+2]=u.z; w[j4*4+3]=u.w;
    }
    if (n >= 49){
      #pragma unroll
      for (int j = 0; j < 16; ++j) w[j] = 0;
    }
    #pragma unroll
    for (int j = 0; j < 16; ++j){
      vt_lds[(2*j  )*72 + n] = (u16)(w[j] & 0xffffu);
      vt_lds[(2*j+1)*72 + n] = (u16)(w[j] >> 16);
    }
  }

  bf16x8 qa[4], kb[4];
  #pragma unroll
  for (int mi = 0; mi < 4; ++mi){
    int row = mi*16 + l15; int t = tokof(row < 49 ? row : 48);
    qa[mi] = *(const bf16x8*)(qkv + (size_t)t*1152 + h*32 + l4*8);
  }
  #pragma unroll
  for (int ni = 0; ni < 4; ++ni){
    int row = ni*16 + l15; int t = tokof(row < 49 ? row : 48);
    kb[ni] = *(const bf16x8*)(qkv + (size_t)t*1152 + 384 + h*32 + l4*8);
  }
  f32x4 s[4][4] = {};
  #pragma unroll
  for (int mi = 0; mi < 4; ++mi)
    #pragma unroll
    for (int ni = 0; ni < 4; ++ni)
      s[mi][ni] = __builtin_amdgcn_mfma_f32_16x16x32_bf16(qa[mi], kb[ni], s[mi][ni], 0, 0, 0);

  __syncthreads();

  int rid_k[4];
  if (SHIFT){
    #pragma unroll
    for (int ni = 0; ni < 4; ++ni) rid_k[ni] = rid_lds[ni*16 + l15];
  }

  const float* bt = btbl + h*4096;
  float den[4][4];
  #pragma unroll
  for (int mi = 0; mi < 4; ++mi){
    #pragma unroll
    for (int r = 0; r < 4; ++r){
      int q = mi*16 + l4*4 + r;
      f32x4 bq = *(const f32x4*)(bt + q*64 + l15*4);
      int ridq = 0;
      if (SHIFT) ridq = rid_lds[q];
      #pragma unroll
      for (int ni = 0; ni < 4; ++ni){
        float v = s[mi][ni][r] * 0.17677669529663687f + bq[ni];
        if (SHIFT) v += (ridq == rid_k[ni]) ? 0.f : -100.f;
        s[mi][ni][r] = v;
      }
      float m0 = fmaxf(fmaxf(s[mi][0][r], s[mi][1][r]), fmaxf(s[mi][2][r], s[mi][3][r]));
      #pragma unroll
      for (int o = 1; o <= 8; o <<= 1) m0 = fmaxf(m0, __shfl_xor(m0, o));
      float d0 = 0.f;
      #pragma unroll
      for (int ni = 0; ni < 4; ++ni){
        float e = __expf(s[mi][ni][r] - m0);
        s[mi][ni][r] = e; d0 += e;
      }
      #pragma unroll
      for (int o = 1; o <= 8; o <<= 1) d0 += __shfl_xor(d0, o);
      den[mi][r] = d0;
    }
  }

  #pragma unroll
  for (int mi = 0; mi < 4; ++mi)
    #pragma unroll
    for (int r = 0; r < 4; ++r){
      int q = mi*16 + l4*4 + r;
      #pragma unroll
      for (int ni = 0; ni < 4; ++ni)
        p_lds[q*72 + ni*16 + l15] = f2b(s[mi][ni][r]);
    }

  __syncthreads();

  f32x4 o2[4][2] = {};
  #pragma unroll
  for (int ks = 0; ks < 2; ++ks){
    bf16x8 vb[2];
    #pragma unroll
    for (int ni = 0; ni < 2; ++ni)
      vb[ni] = *(const bf16x8*)&vt_lds[(ni*16 + l15)*72 + ks*32 + l4*8];
    #pragma unroll
    for (int mi = 0; mi < 4; ++mi){
      bf16x8 pa = *(const bf16x8*)&p_lds[(mi*16 + l15)*72 + ks*32 + l4*8];
      #pragma unroll
      for (int ni = 0; ni < 2; ++ni)
        o2[mi][ni] = __builtin_amdgcn_mfma_f32_16x16x32_bf16(pa, vb[ni], o2[mi][ni], 0, 0, 0);
    }
  }

  #pragma unroll
  for (int mi = 0; mi < 4; ++mi){
    #pragma unroll
    for (int r = 0; r < 4; ++r){
      int q = mi*16 + l4*4 + r;
      if (q < 49){
        float inv = 1.f / den[mi][r];
        long t = tok_lds[q];
        #pragma unroll
        for (int ni = 0; ni < 2; ++ni){
          int d = ni*16 + l15;
          attn_out[t*384 + h*32 + d] = f2b(o2[mi][ni][r] * inv);
        }
      }
    }
  }
}

extern "C" void kernel_launch(void* const* d_in, const int* in_sizes, int n_in,
                              void* d_out, int out_size, void* d_ws, size_t ws_size,
                              hipStream_t stream)
{
  const float* x_in   = (const float*)d_in[0];
  const int*   relidx = (const int*)d_in[2];
  const float* n1g    = (const float*)d_in[3];
  const float* n1b    = (const float*)d_in[4];
  const float* qkvw   = (const float*)d_in[5];
  const float* qkvb   = (const float*)d_in[6];
  const float* rpb    = (const float*)d_in[7];
  const float* pw     = (const float*)d_in[8];
  const float* pb     = (const float*)d_in[9];
  const float* n2g    = (const float*)d_in[10];
  const float* n2b    = (const float*)d_in[11];
  const float* f1w    = (const float*)d_in[12];
  const float* f1b    = (const float*)d_in[13];
  const float* f2w    = (const float*)d_in[14];
  const float* f2bb   = (const float*)d_in[15];
  float* xout = (float*)d_out;

  char* ws = (char*)d_ws;
  u16* wqkv   = (u16*)ws; ws += (size_t)2*1152*384*2;
  u16* wproj  = (u16*)ws; ws += (size_t)2*384*384*2;
  u8*  wfc1q  = (u8*)ws;  ws += (size_t)2*1536*384;
  u8*  wfc2q  = (u8*)ws;  ws += (size_t)2*384*1536;
  u16* bufA   = (u16*)ws; ws += (size_t)M_TOK*1536*2;  // qkv bf16 / h fp8 overlay
  u16* bufB   = (u16*)ws; ws += (size_t)M_TOK*384*2;   // LN1 bf16 / attn_out bf16
  u8*  bufD   = (u8*)ws;  ws += (size_t)M_TOK*384;     // LN2 fp8
  float* btbl = (float*)(bufA + (size_t)M_TOK*1152);   // tail of bufA during attn
  u8* h8 = (u8*)bufA;                                  // FC1 out overlays qkv

  // convert weights: qkv/proj -> bf16; fc1 -> fp8; fc2 -> fp8 k-permuted
  {
    int n;
    n = 2*1152*384;  cvtw  <<<dim3((n/4+255)/256), dim3(256), 0, stream>>>(qkvw, wqkv,  n/4);
    n = 2*384*384;   cvtw  <<<dim3((n/4+255)/256), dim3(256), 0, stream>>>(pw,   wproj, n/4);
    n = 2*1536*384;  cvtw8 <<<dim3((n/4+255)/256), dim3(256), 0, stream>>>(f1w,  wfc1q, n/4);
    n = 2*384*1536;  cvtw8p<<<dim3((n/4+255)/256), dim3(256), 0, stream>>>(f2w,  wfc2q, 2*384, 1536);
  }

  for (int i = 0; i < 2; ++i){
    const float* xi = (i == 0) ? x_in : xout;
    // LN1 -> bufB (bf16)
    ln_kernel<0><<<dim3(2048), dim3(256), 0, stream>>>(xi, n1g + i*384, n1b + i*384, bufB, M_TOK);
    // QKV (bf16): bufB @ wqkv^T -> bufA  [M,1152]   grid 3528
    gemm_bt<0><<<dim3(3528), dim3(256), 0, stream>>>(
        bufB, wqkv + (size_t)i*1152*384, qkvb + i*1152, nullptr, bufA, M_TOK, 1152, 384);
    // bias table
    build_btbl<<<dim3(768), dim3(64), 0, stream>>>(rpb + (size_t)i*169*12, relidx, btbl);
    // attention: bufA -> bufB [M,384] bf16
    if (i == 0)
      attn_mfma<0><<<dim3(12288), dim3(64), 0, stream>>>(bufA, btbl, bufB);
    else
      attn_mfma<3><<<dim3(12288), dim3(64), 0, stream>>>(bufA, btbl, bufB);
    // proj + residual (bf16): xout = xi + bufB @ wproj^T + pb   grid 1176
    gemm_bt<2><<<dim3(1176), dim3(256), 0, stream>>>(
        bufB, wproj + (size_t)i*384*384, pb + i*384, xi, xout, M_TOK, 384, 384);
    // LN2 -> bufD (fp8)
    ln_kernel<1><<<dim3(2048), dim3(256), 0, stream>>>(xout, n2g + i*384, n2b + i*384, bufD, M_TOK);
    // FC1 (fp8) + gelu: bufD @ wfc1q^T -> h8 [M,1536] fp8 (permuted cols)  grid 4704
    gemm_f8<1><<<dim3(4704), dim3(256), 0, stream>>>(
        bufD, wfc1q + (size_t)i*1536*384, f1b + i*1536, nullptr, h8, M_TOK, 1536, 384);
    // FC2 (fp8, k-permuted both sides) + residual: xout += h8 @ wfc2q^T + f2b  grid 1176
    gemm_f8<2><<<dim3(1176), dim3(256), 0, stream>>>(
        h8, wfc2q + (size_t)i*384*1536, f2bb + i*384, xout, xout, M_TOK, 384, 1536);
  }
  (void)in_sizes; (void)n_in; (void)out_size; (void)ws_size;
}

// Round 16
// 915.303 us; speedup vs baseline: 1.0267x; 1.0140x over previous
//
#include <hip/hip_runtime.h>
#include <hip/hip_fp8.h>
#include <math.h>

typedef unsigned char  u8;
typedef unsigned short u16;
typedef unsigned int   u32;
typedef long long      i64;
typedef __attribute__((ext_vector_type(4))) float f32x4;
typedef __attribute__((ext_vector_type(8))) short bf16x8;

#define M_TOK 50176
#define CDIM  384

__device__ __forceinline__ u16 f2b(float f){
  union { float f; u32 u; } v; v.f = f;
  u32 r = v.u + 0x7fffu + ((v.u >> 16) & 1u);
  return (u16)(r >> 16);
}
__device__ __forceinline__ u32 pack2(float a, float b){
  return (u32)f2b(a) | ((u32)f2b(b) << 16);
}
__device__ __forceinline__ u8 f2q(float v){          // f32 -> fp8 e4m3 (OCP), cold paths only
  __hip_fp8_e4m3 t(v);
  return *reinterpret_cast<u8*>(&t);
}
// HW packed f32x2 -> 2 fp8 bytes (OCP e4m3 on gfx950). byte0 = a, byte1 = b.
__device__ __forceinline__ u32 cvt2q(float a, float b){
  u32 p = 0;
  asm("v_cvt_pk_fp8_f32 %0, %1, %2" : "+v"(p) : "v"(a), "v"(b));
  return p & 0xffffu;
}
// tanh-form GELU via hardware exp; |dev| vs exact erf-GELU < 3.5e-4
// (negligible under fp8-e4m3 quantization of h). NaN-safe at +-inf exp.
__device__ __forceinline__ float gelu(float x){
  float u = x * (0.7978845608028654f + 0.035677408136300125f * x * x);
  float e = __expf(2.f * u);
  float th = 1.f - 2.f / (e + 1.f);
  return 0.5f * x * (1.f + th);
}

__device__ __forceinline__ void gload_lds16(const void* g, void* l){
  __builtin_amdgcn_global_load_lds((const __attribute__((address_space(1))) u32*)g,
                                   (__attribute__((address_space(3))) u32*)l, 16, 0, 0);
}

// ---------------- weight convert f32 -> bf16 ----------------
__global__ void cvtw(const float* __restrict__ in, u16* __restrict__ out, int n4){
  int i = blockIdx.x * 256 + threadIdx.x;
  if (i < n4){
    float4 v = ((const float4*)in)[i];
    uint2 o; o.x = pack2(v.x, v.y); o.y = pack2(v.z, v.w);
    ((uint2*)out)[i] = o;
  }
}
// ---------------- weight convert f32 -> fp8 e4m3 (natural order) --------
__global__ void cvtw8(const float* __restrict__ in, u8* __restrict__ out, int n4){
  int i = blockIdx.x * 256 + threadIdx.x;
  if (i < n4){
    float4 v = ((const float4*)in)[i];
    u32 o = cvt2q(v.x, v.y) | (cvt2q(v.z, v.w) << 16);
    ((u32*)out)[i] = o;
  }
}
// ---------------- weight convert f32 -> fp8 with per-64 k-permutation ----
// out[row][g*64 + (j%16)*4 + j/16] = fp8(in[row][g*64 + j]).
// Matches FC1's permuted-h store order; since h (A) and W2 (B) share the
// same k-bijection, FC2's dot products are unchanged.
__global__ void cvtw8p(const float* __restrict__ in, u8* __restrict__ out,
                       int rows, int cols){
  int idx = blockIdx.x * 256 + threadIdx.x;      // output u32 index
  if (idx < rows * (cols >> 2)){
    int byte0 = idx << 2;
    int row = byte0 / cols, cb = byte0 % cols;
    int g = cb >> 6, s = (cb & 63) >> 2;         // pos 4s+m <- j = m*16+s
    const float* rp = in + (size_t)row * cols + g*64;
    u32 w = cvt2q(rp[s], rp[16 + s]) | (cvt2q(rp[32 + s], rp[48 + s]) << 16);
    ((u32*)out)[idx] = w;
  }
}

// ---------------- LayerNorm (fp32 in, bf16 or fp8 out) ----------------
template<int F8>
__global__ __launch_bounds__(256) void ln_kernel(
    const float* __restrict__ x, const float* __restrict__ g,
    const float* __restrict__ b, void* __restrict__ out, int ntok)
{
  int wave = threadIdx.x >> 6, lane = threadIdx.x & 63;
  for (long t = blockIdx.x * 4 + wave; t < ntok; t += (long)gridDim.x * 4){
    const float* xr = x + t * CDIM;
    float v[6]; float s = 0.f, ss = 0.f;
    #pragma unroll
    for (int j = 0; j < 6; ++j){ v[j] = xr[j*64 + lane]; s += v[j]; ss += v[j]*v[j]; }
    #pragma unroll
    for (int o = 32; o >= 1; o >>= 1){ s += __shfl_xor(s, o); ss += __shfl_xor(ss, o); }
    float mean = s * (1.f/384.f);
    float var  = ss * (1.f/384.f) - mean*mean;
    float rs   = rsqrtf(var + 1e-5f);
    if (F8){
      float nv[6];
      #pragma unroll
      for (int j = 0; j < 6; ++j){
        int c = j*64 + lane;
        nv[j] = (v[j] - mean) * rs * g[c] + b[c];
      }
      #pragma unroll
      for (int j = 0; j < 6; j += 2){
        u32 p = cvt2q(nv[j], nv[j+1]);           // HW packed convert
        ((u8*)out)[t*CDIM + j*64 + lane]     = (u8)(p & 0xff);
        ((u8*)out)[t*CDIM + (j+1)*64 + lane] = (u8)((p >> 8) & 0xff);
      }
    } else {
      #pragma unroll
      for (int j = 0; j < 6; ++j){
        int c = j*64 + lane;
        ((u16*)out)[t*CDIM + c] = f2b((v[j] - mean) * rs * g[c] + b[c]);
      }
    }
  }
}

// ---------------- bf16 GEMM (R6 proven, verbatim) ----------------
// EPI 0: bf16 store (bias)   2: f32 store (bias + resid)
template<int EPI>
__global__ __launch_bounds__(256, 4) void gemm_bt(
    const u16* __restrict__ A, const u16* __restrict__ Wt,
    const float* __restrict__ bias, const float* __restrict__ resid,
    void* __restrict__ outp, int M, int N, int K)
{
  __shared__ __align__(16) u16 smem[16384];   // 32 KB: [A0|A1|B0|B1] / epi 128x128
  const int tid  = threadIdx.x;
  const int wave = tid >> 6, lane = tid & 63;
  const int nbn  = N >> 7;
  const int nwg = gridDim.x;
  const int q8 = nwg >> 3, r8 = nwg & 7, xcd = blockIdx.x & 7, o8 = blockIdx.x >> 3;
  const int sid = (xcd < r8 ? xcd*(q8+1) : r8*(q8+1) + (xcd-r8)*q8) + o8;
  const int bm = sid / nbn, bn = sid % nbn;
  const int wr = wave >> 1, wc = wave & 1;
  const int l15 = lane & 15, l4 = lane >> 4;
  const int srow = tid >> 2, sch = tid & 3;

  f32x4 acc[4][4] = {};

  auto STAGE = [&](int buf, int kt){
    u16* lAp = smem + buf*4096;
    u16* lBp = smem + 8192 + buf*4096;
    #pragma unroll
    for (int it = 0; it < 2; ++it){
      int row = it*64 + srow;
      int chs = sch ^ ((srow >> 1) & 3);
      const u16* ga = A  + (size_t)(bm*128 + row) * K + kt + chs*8;
      const u16* gb = Wt + (size_t)(bn*128 + row) * K + kt + chs*8;
      gload_lds16(ga, &lAp[(it*256 + wave*64) * 8]);
      gload_lds16(gb, &lBp[(it*256 + wave*64) * 8]);
    }
  };

  const int NK = K >> 5;
  STAGE(0, 0);

  int cur = 0;
  for (int ki = 0; ki < NK; ++ki){
    if (ki + 1 < NK){
      STAGE(cur ^ 1, (ki + 1) * 32);
      asm volatile("s_waitcnt vmcnt(4)" ::: "memory");
    } else {
      asm volatile("s_waitcnt vmcnt(0)" ::: "memory");
    }
    __builtin_amdgcn_s_barrier();
    const u16* lAp = smem + cur*4096;
    const u16* lBp = smem + 8192 + cur*4096;
    bf16x8 af[4], bfr[4];
    const int rc = (l4 ^ ((l15 >> 1) & 3)) * 8;
    #pragma unroll
    for (int mi = 0; mi < 4; ++mi)
      af[mi] = *(const bf16x8*)&lAp[(wr*64 + mi*16 + l15)*32 + rc];
    #pragma unroll
    for (int ni = 0; ni < 4; ++ni)
      bfr[ni] = *(const bf16x8*)&lBp[(wc*64 + ni*16 + l15)*32 + rc];
    #pragma unroll
    for (int mi = 0; mi < 4; ++mi)
      #pragma unroll
      for (int ni = 0; ni < 4; ++ni)
        acc[mi][ni] = __builtin_amdgcn_mfma_f32_16x16x32_bf16(af[mi], bfr[ni], acc[mi][ni], 0, 0, 0);
    __builtin_amdgcn_s_barrier();
    cur ^= 1;
  }

  if (EPI == 2){
    #pragma unroll
    for (int ni = 0; ni < 4; ++ni){
      int col = bn*128 + wc*64 + ni*16 + l15;
      float bb = bias[col];
      #pragma unroll
      for (int mi = 0; mi < 4; ++mi){
        int row0 = bm*128 + wr*64 + mi*16 + l4*4;
        #pragma unroll
        for (int r = 0; r < 4; ++r){
          long off = (long)(row0 + r) * N + col;
          ((float*)outp)[off] = resid[off] + acc[mi][ni][r] + bb;
        }
      }
    }
  } else {
    #pragma unroll
    for (int ni = 0; ni < 4; ++ni){
      int colL = wc*64 + ni*16 + l15;
      float bb = bias[bn*128 + colL];
      int colS = colL ^ (l4*16);
      #pragma unroll
      for (int mi = 0; mi < 4; ++mi){
        int rowL = wr*64 + mi*16 + l4*4;
        #pragma unroll
        for (int r = 0; r < 4; ++r){
          float v = acc[mi][ni][r] + bb;
          smem[(rowL + r)*128 + colS] = f2b(v);
        }
      }
    }
    __syncthreads();
    const u32* eb = (const u32*)smem;
    u32* og = (u32*)outp;
    const int nW = N >> 1;
    #pragma unroll
    for (int it = 0; it < 32; ++it){
      int row = wave*32 + it;
      u32 w = eb[row*64 + (lane ^ (((row >> 2) & 3) * 8))];
      __builtin_nontemporal_store(w, &og[(size_t)(bm*128 + row) * nW + bn*64 + lane]);
    }
  }
}

// ---------------- fp8 GEMM: 3-deep pipeline (2 stages in flight) ----------
// R15 showed fp8 K-loop is LATENCY-floored, not BW-bound (half the bytes of
// bf16 but far above the 73us staged-byte floor): 1-deep prefetch gives only
// ~320cy MFMA cover vs 300-900cy load latency. 3 LDS buffers (24KB, still 4
// blocks/CU - R7's depth mistake corrected), issue stage ki+2 then vmcnt(4)
// (6 outstanding - 4 => stage ki drained): 2 K-steps of cover.
// 16B slots permuted by involution slot' = s ^ ((s>>3)&7) on stage-source
// AND frag read -> 2-way bank aliasing (free).
// EPI 1: h out (bias+exp-GELU) via HW v_cvt_pk_fp8_f32, permuted-col u32 NT
//        stores; W2 pre-permuted to match (cvtw8p).
// EPI 2: f32 bias+resid direct.
template<int EPI>
__global__ __launch_bounds__(256, 4) void gemm_f8(
    const u8* __restrict__ A, const u8* __restrict__ Wt,
    const float* __restrict__ bias, const float* __restrict__ resid,
    void* __restrict__ outp, int M, int N, int K)
{
  __shared__ __align__(16) u8 smem[24576];    // 3 bufs x (A 4KB + B 4KB)
  const int tid  = threadIdx.x;
  const int wave = tid >> 6, lane = tid & 63;
  const int nbn  = N >> 7;
  const int nwg = gridDim.x;
  const int q8 = nwg >> 3, r8 = nwg & 7, xcd = blockIdx.x & 7, o8 = blockIdx.x >> 3;
  const int sid = (xcd < r8 ? xcd*(q8+1) : r8*(q8+1) + (xcd-r8)*q8) + o8;
  const int bm = sid / nbn, bn = sid % nbn;
  const int wr = wave >> 1, wc = wave & 1;
  const int l15 = lane & 15, l4 = lane >> 4;

  f32x4 acc[4][4] = {};

  const int gsl = tid ^ ((tid >> 3) & 7);     // involution: global chunk for slot tid
  const int grow = gsl >> 1, gc16 = gsl & 1;

  auto STAGE = [&](int buf, int kt){          // 2 gload_lds16 per thread
    const u8* ga = A  + (size_t)(bm*128 + grow) * K + kt + gc16*16;
    const u8* gb = Wt + (size_t)(bn*128 + grow) * K + kt + gc16*16;
    gload_lds16(ga, &smem[buf*8192 + tid*16]);
    gload_lds16(gb, &smem[buf*8192 + 4096 + tid*16]);
  };

  const int NK = K >> 5;
  STAGE(0, 0);
  if (NK > 1) STAGE(1, 32);

  // per-thread frag slot offsets (loop-invariant)
  const int c16 = l4 >> 1, half8 = (l4 & 1) * 8;
  int spA[4], spB[4];
  #pragma unroll
  for (int mi = 0; mi < 4; ++mi){
    int s = (wr*64 + mi*16 + l15)*2 + c16;
    spA[mi] = (s ^ ((s >> 3) & 7)) * 16 + half8;
  }
  #pragma unroll
  for (int ni = 0; ni < 4; ++ni){
    int s = (wc*64 + ni*16 + l15)*2 + c16;
    spB[ni] = (s ^ ((s >> 3) & 7)) * 16 + half8;
  }

  int cur = 0;
  for (int ki = 0; ki < NK; ++ki){
    if (ki + 2 < NK){
      int nb = cur + 2; if (nb >= 3) nb -= 3;
      STAGE(nb, (ki + 2) * 32);
      asm volatile("s_waitcnt vmcnt(4)" ::: "memory");  // stage ki drained; 2 in flight
    } else if (ki + 1 < NK){
      asm volatile("s_waitcnt vmcnt(2)" ::: "memory");  // stage ki drained; 1 in flight
    } else {
      asm volatile("s_waitcnt vmcnt(0)" ::: "memory");
    }
    __builtin_amdgcn_s_barrier();
    const u8* lAp = smem + cur*8192;
    const u8* lBp = smem + cur*8192 + 4096;
    i64 af[4], bf[4];
    #pragma unroll
    for (int mi = 0; mi < 4; ++mi)
      af[mi] = *(const i64*)&lAp[spA[mi]];
    #pragma unroll
    for (int ni = 0; ni < 4; ++ni)
      bf[ni] = *(const i64*)&lBp[spB[ni]];
    #pragma unroll
    for (int mi = 0; mi < 4; ++mi)
      #pragma unroll
      for (int ni = 0; ni < 4; ++ni)
        acc[mi][ni] = __builtin_amdgcn_mfma_f32_16x16x32_fp8_fp8(af[mi], bf[ni], acc[mi][ni], 0, 0, 0);
    __builtin_amdgcn_s_barrier();
    cur += 1; if (cur >= 3) cur = 0;
  }

  if (EPI == 2){
    // f32 + residual: 16 lanes x 4B = full 64B lines
    #pragma unroll
    for (int ni = 0; ni < 4; ++ni){
      int col = bn*128 + wc*64 + ni*16 + l15;
      float bb = bias[col];
      #pragma unroll
      for (int mi = 0; mi < 4; ++mi){
        int row0 = bm*128 + wr*64 + mi*16 + l4*4;
        #pragma unroll
        for (int r = 0; r < 4; ++r){
          long off = (long)(row0 + r) * N + col;
          ((float*)outp)[off] = resid[off] + acc[mi][ni][r] + bb;
        }
      }
    }
  } else {
    // h out (bias + GELU), HW packed cvt, permuted-order u32 NT stores.
    // lane's 4 ni-values -> byte pos wc*64 + l15*4 + ni of the row.
    u32* og = (u32*)outp;
    const int nW = N >> 2;
    float bb[4];
    #pragma unroll
    for (int ni = 0; ni < 4; ++ni) bb[ni] = bias[bn*128 + wc*64 + ni*16 + l15];
    const int wordc = (bn*128 + wc*64 + l15*4) >> 2;
    #pragma unroll
    for (int mi = 0; mi < 4; ++mi){
      int row0 = bm*128 + wr*64 + mi*16 + l4*4;
      #pragma unroll
      for (int r = 0; r < 4; ++r){
        float v0 = gelu(acc[mi][0][r] + bb[0]);
        float v1 = gelu(acc[mi][1][r] + bb[1]);
        float v2 = gelu(acc[mi][2][r] + bb[2]);
        float v3 = gelu(acc[mi][3][r] + bb[3]);
        u32 w = cvt2q(v0, v1) | (cvt2q(v2, v3) << 16);
        __builtin_nontemporal_store(w, &og[(size_t)(row0 + r) * nW + wordc]);
      }
    }
  }
}

// ---------------- bias table (fragment order) ----------------
__global__ void build_btbl(const float* __restrict__ rpb, const int* __restrict__ ridx,
                           float* __restrict__ btbl){
  int q = blockIdx.x & 63, h = blockIdx.x >> 6;
  int l = threadIdx.x;
  float v = -1e9f;
  if (q < 49){
    int key = (l & 3) * 16 + (l >> 2);
    if (key < 49) v = rpb[ridx[q*49 + key] * 12 + h];
  }
  btbl[(h*64 + q)*64 + l] = v;
}

// ---------------- MFMA windowed attention (unchanged) ----------------
template<int SHIFT>
__global__ __launch_bounds__(64) void attn_mfma(
    const u16* __restrict__ qkv, const float* __restrict__ btbl,
    u16* __restrict__ attn_out)
{
  __shared__ __align__(16) u16 p_lds[64*72];
  __shared__ __align__(16) u16 vt_lds[32*72];
  __shared__ int tok_lds[64];
  __shared__ int rid_lds[64];

  const int bid = blockIdx.x;
  const int h   = bid % 12;
  const int win = bid / 12;
  const int b   = win >> 6, wl = win & 63;
  const int wy  = wl >> 3,  wx = wl & 7;
  const int lane = threadIdx.x;
  const int l15 = lane & 15, l4 = lane >> 4;

  auto tokof = [&](int n)->int{
    int r = (n * 9363) >> 16;
    int c = n - r * 7;
    int hh = wy*7 + r + SHIFT; if (hh >= 56) hh -= 56;
    int ww = wx*7 + c + SHIFT; if (ww >= 56) ww -= 56;
    return b*3136 + hh*56 + ww;
  };

  {
    const int n  = lane;
    const int nc = n < 49 ? n : 48;
    const int t  = tokof(nc);
    tok_lds[n] = t;
    if (SHIFT){
      int r = (nc * 9363) >> 16, c = nc - r*7;
      int gh = wy*7 + r, gw = wx*7 + c;
      int rh = gh <= 48 ? 0 : (gh <= 52 ? 1 : 2);
      int rw = gw <= 48 ? 0 : (gw <= 52 ? 1 : 2);
      rid_lds[n] = rh*3 + rw;
    }
    const uint4* vp = (const uint4*)(qkv + (size_t)t*1152 + 768 + h*32);
    u32 w[16];
    #pragma unroll
    for (int j4 = 0; j4 < 4; ++j4){
      uint4 u = vp[j4];
      w[j4*4+0]=u.x; w[j4*4+1]=u.y; w[j4*4+2]=u.z; w[j4*4+3]=u.w;
    }
    if (n >= 49){
      #pragma unroll
      for (int j = 0; j < 16; ++j) w[j] = 0;
    }
    #pragma unroll
    for (int j = 0; j < 16; ++j){
      vt_lds[(2*j  )*72 + n] = (u16)(w[j] & 0xffffu);
      vt_lds[(2*j+1)*72 + n] = (u16)(w[j] >> 16);
    }
  }

  bf16x8 qa[4], kb[4];
  #pragma unroll
  for (int mi = 0; mi < 4; ++mi){
    int row = mi*16 + l15; int t = tokof(row < 49 ? row : 48);
    qa[mi] = *(const bf16x8*)(qkv + (size_t)t*1152 + h*32 + l4*8);
  }
  #pragma unroll
  for (int ni = 0; ni < 4; ++ni){
    int row = ni*16 + l15; int t = tokof(row < 49 ? row : 48);
    kb[ni] = *(const bf16x8*)(qkv + (size_t)t*1152 + 384 + h*32 + l4*8);
  }
  f32x4 s[4][4] = {};
  #pragma unroll
  for (int mi = 0; mi < 4; ++mi)
    #pragma unroll
    for (int ni = 0; ni < 4; ++ni)
      s[mi][ni] = __builtin_amdgcn_mfma_f32_16x16x32_bf16(qa[mi], kb[ni], s[mi][ni], 0, 0, 0);

  __syncthreads();

  int rid_k[4];
  if (SHIFT){
    #pragma unroll
    for (int ni = 0; ni < 4; ++ni) rid_k[ni] = rid_lds[ni*16 + l15];
  }

  const float* bt = btbl + h*4096;
  float den[4][4];
  #pragma unroll
  for (int mi = 0; mi < 4; ++mi){
    #pragma unroll
    for (int r = 0; r < 4; ++r){
      int q = mi*16 + l4*4 + r;
      f32x4 bq = *(const f32x4*)(bt + q*64 + l15*4);
      int ridq = 0;
      if (SHIFT) ridq = rid_lds[q];
      #pragma unroll
      for (int ni = 0; ni < 4; ++ni){
        float v = s[mi][ni][r] * 0.17677669529663687f + bq[ni];
        if (SHIFT) v += (ridq == rid_k[ni]) ? 0.f : -100.f;
        s[mi][ni][r] = v;
      }
      float m0 = fmaxf(fmaxf(s[mi][0][r], s[mi][1][r]), fmaxf(s[mi][2][r], s[mi][3][r]));
      #pragma unroll
      for (int o = 1; o <= 8; o <<= 1) m0 = fmaxf(m0, __shfl_xor(m0, o));
      float d0 = 0.f;
      #pragma unroll
      for (int ni = 0; ni < 4; ++ni){
        float e = __expf(s[mi][ni][r] - m0);
        s[mi][ni][r] = e; d0 += e;
      }
      #pragma unroll
      for (int o = 1; o <= 8; o <<= 1) d0 += __shfl_xor(d0, o);
      den[mi][r] = d0;
    }
  }

  #pragma unroll
  for (int mi = 0; mi < 4; ++mi)
    #pragma unroll
    for (int r = 0; r < 4; ++r){
      int q = mi*16 + l4*4 + r;
      #pragma unroll
      for (int ni = 0; ni < 4; ++ni)
        p_lds[q*72 + ni*16 + l15] = f2b(s[mi][ni][r]);
    }

  __syncthreads();

  f32x4 o2[4][2] = {};
  #pragma unroll
  for (int ks = 0; ks < 2; ++ks){
    bf16x8 vb[2];
    #pragma unroll
    for (int ni = 0; ni < 2; ++ni)
      vb[ni] = *(const bf16x8*)&vt_lds[(ni*16 + l15)*72 + ks*32 + l4*8];
    #pragma unroll
    for (int mi = 0; mi < 4; ++mi){
      bf16x8 pa = *(const bf16x8*)&p_lds[(mi*16 + l15)*72 + ks*32 + l4*8];
      #pragma unroll
      for (int ni = 0; ni < 2; ++ni)
        o2[mi][ni] = __builtin_amdgcn_mfma_f32_16x16x32_bf16(pa, vb[ni], o2[mi][ni], 0, 0, 0);
    }
  }

  #pragma unroll
  for (int mi = 0; mi < 4; ++mi){
    #pragma unroll
    for (int r = 0; r < 4; ++r){
      int q = mi*16 + l4*4 + r;
      if (q < 49){
        float inv = 1.f / den[mi][r];
        long t = tok_lds[q];
        #pragma unroll
        for (int ni = 0; ni < 2; ++ni){
          int d = ni*16 + l15;
          attn_out[t*384 + h*32 + d] = f2b(o2[mi][ni][r] * inv);
        }
      }
    }
  }
}

extern "C" void kernel_launch(void* const* d_in, const int* in_sizes, int n_in,
                              void* d_out, int out_size, void* d_ws, size_t ws_size,
                              hipStream_t stream)
{
  const float* x_in   = (const float*)d_in[0];
  const int*   relidx = (const int*)d_in[2];
  const float* n1g    = (const float*)d_in[3];
  const float* n1b    = (const float*)d_in[4];
  const float* qkvw   = (const float*)d_in[5];
  const float* qkvb   = (const float*)d_in[6];
  const float* rpb    = (const float*)d_in[7];
  const float* pw     = (const float*)d_in[8];
  const float* pb     = (const float*)d_in[9];
  const float* n2g    = (const float*)d_in[10];
  const float* n2b    = (const float*)d_in[11];
  const float* f1w    = (const float*)d_in[12];
  const float* f1b    = (const float*)d_in[13];
  const float* f2w    = (const float*)d_in[14];
  const float* f2bb   = (const float*)d_in[15];
  float* xout = (float*)d_out;

  char* ws = (char*)d_ws;
  u16* wqkv   = (u16*)ws; ws += (size_t)2*1152*384*2;
  u16* wproj  = (u16*)ws; ws += (size_t)2*384*384*2;
  u8*  wfc1q  = (u8*)ws;  ws += (size_t)2*1536*384;
  u8*  wfc2q  = (u8*)ws;  ws += (size_t)2*384*1536;
  u16* bufA   = (u16*)ws; ws += (size_t)M_TOK*1536*2;  // qkv bf16 / h fp8 overlay
  u16* bufB   = (u16*)ws; ws += (size_t)M_TOK*384*2;   // LN1 bf16 / attn_out bf16
  u8*  bufD   = (u8*)ws;  ws += (size_t)M_TOK*384;     // LN2 fp8
  float* btbl = (float*)(bufA + (size_t)M_TOK*1152);   // tail of bufA during attn
  u8* h8 = (u8*)bufA;                                  // FC1 out overlays qkv

  // convert weights: qkv/proj -> bf16; fc1 -> fp8; fc2 -> fp8 k-permuted
  {
    int n;
    n = 2*1152*384;  cvtw  <<<dim3((n/4+255)/256), dim3(256), 0, stream>>>(qkvw, wqkv,  n/4);
    n = 2*384*384;   cvtw  <<<dim3((n/4+255)/256), dim3(256), 0, stream>>>(pw,   wproj, n/4);
    n = 2*1536*384;  cvtw8 <<<dim3((n/4+255)/256), dim3(256), 0, stream>>>(f1w,  wfc1q, n/4);
    n = 2*384*1536;  cvtw8p<<<dim3((n/4+255)/256), dim3(256), 0, stream>>>(f2w,  wfc2q, 2*384, 1536);
  }

  for (int i = 0; i < 2; ++i){
    const float* xi = (i == 0) ? x_in : xout;
    // LN1 -> bufB (bf16)
    ln_kernel<0><<<dim3(2048), dim3(256), 0, stream>>>(xi, n1g + i*384, n1b + i*384, bufB, M_TOK);
    // QKV (bf16): bufB @ wqkv^T -> bufA  [M,1152]   grid 3528
    gemm_bt<0><<<dim3(3528), dim3(256), 0, stream>>>(
        bufB, wqkv + (size_t)i*1152*384, qkvb + i*1152, nullptr, bufA, M_TOK, 1152, 384);
    // bias table
    build_btbl<<<dim3(768), dim3(64), 0, stream>>>(rpb + (size_t)i*169*12, relidx, btbl);
    // attention: bufA -> bufB [M,384] bf16
    if (i == 0)
      attn_mfma<0><<<dim3(12288), dim3(64), 0, stream>>>(bufA, btbl, bufB);
    else
      attn_mfma<3><<<dim3(12288), dim3(64), 0, stream>>>(bufA, btbl, bufB);
    // proj + residual (bf16): xout = xi + bufB @ wproj^T + pb   grid 1176
    gemm_bt<2><<<dim3(1176), dim3(256), 0, stream>>>(
        bufB, wproj + (size_t)i*384*384, pb + i*384, xi, xout, M_TOK, 384, 384);
    // LN2 -> bufD (fp8)
    ln_kernel<1><<<dim3(2048), dim3(256), 0, stream>>>(xout, n2g + i*384, n2b + i*384, bufD, M_TOK);
    // FC1 (fp8, 3-deep) + gelu: bufD @ wfc1q^T -> h8 [M,1536] fp8 (permuted cols)  grid 4704
    gemm_f8<1><<<dim3(4704), dim3(256), 0, stream>>>(
        bufD, wfc1q + (size_t)i*1536*384, f1b + i*1536, nullptr, h8, M_TOK, 1536, 384);
    // FC2 (fp8, 3-deep, k-permuted both sides) + residual: xout += h8 @ wfc2q^T + f2b  grid 1176
    gemm_f8<2><<<dim3(1176), dim3(256), 0, stream>>>(
        h8, wfc2q + (size_t)i*384*1536, f2bb + i*384, xout, xout, M_TOK, 384, 1536);
  }
  (void)in_sizes; (void)n_in; (void)out_size; (void)ws_size;
}